// Round 10
// baseline (354.141 us; speedup 1.0000x reference)
//
#include <hip/hip_runtime.h>
#include <math.h>

#define BB 4
#define NN 4096
#define DD 128
#define KK 8
#define NBLK 12

typedef __attribute__((ext_vector_type(8))) short short8;
typedef __attribute__((ext_vector_type(4))) float f32x4;

__device__ inline ushort bf16_rn(float x) {
    uint u = __float_as_uint(x);
    u = (u + 0x7FFFu + ((u >> 16) & 1u)) >> 16;
    return (ushort)u;
}
__device__ inline float bf16_f(ushort h) { return __uint_as_float(((uint)h) << 16); }

// ---------------- kNN: wave-global top-8 with rare-event inserts ----------
// dist emulates reference f32: (sq[n] - 2*inner) + sq[m], RN, no FMA.
// One wave per query. The top-8 (d,idx) lives wave-uniform in registers.
// Bootstrap: exact top-8 of chunk 0 (per-lane sorted-4 + butterfly merge).
// Scan: candidates passing d<=thr (thr = exact global 8th) are rare (~27
// total); each is broadcast and inserted with lexicographic (d,idx) order —
// identical selection to stable top_k.
__global__ __launch_bounds__(512) void knn_kernel(const float* __restrict__ xyz,
                                                  int* __restrict__ idx) {
    __shared__ float xs[NN], ys[NN], zs[NN], sq[NN];
    const int b = blockIdx.y;
    const float* xb = xyz + (size_t)b * 3 * NN;
    for (int i = threadIdx.x; i < NN; i += 512) {
        float x = xb[i], y = xb[NN + i], z = xb[2 * NN + i];
        xs[i] = x; ys[i] = y; zs[i] = z;
        sq[i] = __fadd_rn(__fadd_rn(__fmul_rn(x, x), __fmul_rn(y, y)),
                          __fmul_rn(z, z));
    }
    __syncthreads();

    const int wave = threadIdx.x >> 6;
    const int lane = threadIdx.x & 63;
    const int n = blockIdx.x * 8 + wave;
    const float qx = xs[n], qy = ys[n], qz = zs[n], qsq = sq[n];

#define DIST(cx, cy, cz, cq)                                                  \
    __fadd_rn(__fsub_rn(qsq, __fmul_rn(2.0f,                                  \
        __fadd_rn(__fadd_rn(__fmul_rn(qx, (cx)), __fmul_rn(qy, (cy))),        \
                  __fmul_rn(qz, (cz))))), (cq))

    // ---- bootstrap: exact top-8 of candidates 0..255 ----
    float ld[4]; int lid[4];
    {
        const int m0 = lane * 4;
        const float4 vx = *(const float4*)&xs[m0];
        const float4 vy = *(const float4*)&ys[m0];
        const float4 vz = *(const float4*)&zs[m0];
        const float4 vq = *(const float4*)&sq[m0];
#pragma unroll
        for (int e = 0; e < 4; ++e) {
            ld[e] = DIST((&vx.x)[e], (&vy.x)[e], (&vz.x)[e], (&vq.x)[e]);
            lid[e] = m0 + e;
        }
        // sort-4 network, lexicographic (d, idx)
#define CAS(a, c)                                                             \
        {                                                                     \
            bool sw = ld[c] < ld[a] || (ld[c] == ld[a] && lid[c] < lid[a]);   \
            float td = sw ? ld[c] : ld[a];  float tD = sw ? ld[a] : ld[c];    \
            int   ti = sw ? lid[c] : lid[a]; int  tI = sw ? lid[a] : lid[c];  \
            ld[a] = td; ld[c] = tD; lid[a] = ti; lid[c] = tI;                 \
        }
        CAS(0, 1) CAS(2, 3) CAS(0, 2) CAS(1, 3) CAS(1, 2)
#undef CAS
    }

    float d[KK]; int id[KK];
#pragma unroll
    for (int it = 0; it < KK; ++it) {
        float hd = ld[0];
        int hi = lid[0];
#pragma unroll
        for (int s = 32; s; s >>= 1) {
            float od = __shfl_xor(hd, s, 64);
            int oi = __shfl_xor(hi, s, 64);
            if (od < hd || (od == hd && oi < hi)) { hd = od; hi = oi; }
        }
        d[it] = hd; id[it] = hi;                    // wave-uniform
        if (hd == ld[0] && hi == lid[0]) {          // winner lane pops
#pragma unroll
            for (int t = 0; t < 3; ++t) { ld[t] = ld[t + 1]; lid[t] = lid[t + 1]; }
            ld[3] = INFINITY; lid[3] = 0x7fffffff;
        }
    }
    float thr = d[KK - 1];

    // ---- scan chunks 1..15: rare-event inserts ----
    for (int j = 1; j < NN / 256; ++j) {
        const int m0 = j * 256 + lane * 4;
        const float4 vx = *(const float4*)&xs[m0];
        const float4 vy = *(const float4*)&ys[m0];
        const float4 vz = *(const float4*)&zs[m0];
        const float4 vq = *(const float4*)&sq[m0];
        float dist[4];
#pragma unroll
        for (int e = 0; e < 4; ++e)
            dist[e] = DIST((&vx.x)[e], (&vy.x)[e], (&vz.x)[e], (&vq.x)[e]);
#pragma unroll
        for (int e = 0; e < 4; ++e) {
            unsigned long long mask = __ballot(dist[e] <= thr);
            while (mask) {
                const int src = __ffsll(mask) - 1;
                mask &= mask - 1;
                const float dl = __shfl(dist[e], src, 64);
                const int il = j * 256 + src * 4 + e;
                if (dl < d[KK - 1] || (dl == d[KK - 1] && il < id[KK - 1])) {
                    d[KK - 1] = dl; id[KK - 1] = il;
#pragma unroll
                    for (int t = KK - 1; t > 0; --t) {
                        bool sw = d[t] < d[t - 1] ||
                                  (d[t] == d[t - 1] && id[t] < id[t - 1]);
                        if (sw) {
                            float td = d[t]; d[t] = d[t - 1]; d[t - 1] = td;
                            int ti = id[t]; id[t] = id[t - 1]; id[t - 1] = ti;
                        }
                    }
                    thr = d[KK - 1];
                }
            }
        }
    }
#undef DIST

    if (lane == 0) {
        int* op = idx + ((size_t)b * NN + n) * KK;
        *(int4*)op       = make_int4(id[0], id[1], id[2], id[3]);
        *(int4*)(op + 4) = make_int4(id[4], id[5], id[6], id[7]);
    }
}

// ---------------- weight prep: Wcat = [W1 | W2] split to bf16 hi/lo -------
__global__ __launch_bounds__(256) void prep_w(const float* __restrict__ w1,
                                              const float* __restrict__ w2,
                                              ushort* __restrict__ whi,
                                              ushort* __restrict__ wlo) {
    const int e = blockIdx.x * 256 + threadIdx.x;     // l*32768 + r*256 + k
    const int l = e >> 15;
    const int rem = e & 32767;
    const int r = rem >> 8;
    const int k = rem & 255;
    float w = (k < 128) ? w1[((size_t)l * 128 + r) * 128 + k]
                        : w2[((size_t)l * 128 + r) * 128 + (k - 128)];
    ushort h = bf16_rn(w);
    whi[e] = h;
    wlo[e] = bf16_rn(w - bf16_f(h));
}

// ---------------- initial transpose: ptsT[b][n][c] = points[b][c][n] ------
__global__ __launch_bounds__(256) void transpose_pts(const float* __restrict__ pts,
                                                     float* __restrict__ ptsT) {
    __shared__ float t[32][33];
    const int b = blockIdx.z;
    const int c0 = blockIdx.y * 32;
    const int n0 = blockIdx.x * 32;
    const int tx = threadIdx.x & 31;
    const int ty = threadIdx.x >> 5;
#pragma unroll
    for (int q = 0; q < 4; ++q)
        t[ty + 8 * q][tx] = pts[((size_t)b * DD + c0 + ty + 8 * q) * NN + n0 + tx];
    __syncthreads();
#pragma unroll
    for (int q = 0; q < 4; ++q)
        ptsT[((size_t)b * NN + n0 + ty + 8 * q) * DD + c0 + tx] = t[tx][ty + 8 * q];
}

// ---------------- fused: gather -> split bf16 -> MFMA -> residual ---------
// 32 cols x 128 rows per block, 256 threads (4 waves), grid 512 (2/CU).
__global__ __launch_bounds__(256) void fused_block(const float* __restrict__ ptsT_in,
                                                   const int* __restrict__ idx,
                                                   const ushort* __restrict__ whi,
                                                   const ushort* __restrict__ wlo,
                                                   float* __restrict__ ptsT_out,
                                                   float* __restrict__ out_std,
                                                   const float* __restrict__ wc,
                                                   const float* __restrict__ wn,
                                                   const float* __restrict__ xyz,
                                                   float* __restrict__ out_xyz,
                                                   const int last) {
    __shared__ __align__(16) char xt[32768];
    __shared__ float sc[32][132];
    char* xt_hi = xt;
    char* xt_lo = xt + 16384;

    const int bid = blockIdx.x;
    const int xcd = bid & 7;
    const int b = xcd >> 1;                         // 2 XCDs per batch
    const int colbase = (((xcd & 1) << 6) + (bid >> 3)) * 32;

    const int w = threadIdx.x >> 6;
    const int lane = threadIdx.x & 63;

    const float* baseT = ptsT_in + (size_t)b * NN * DD;

    // ---- phase A: pipelined gather, split, stage to LDS
    {
        const int row0 = w * 8;
        const int iv = idx[((size_t)b * NN + colbase + row0) * KK + lane];

        float2 c2, u[KK];
        {
            int nb[KK];
#pragma unroll
            for (int j = 0; j < KK; ++j) nb[j] = __shfl(iv, j, 64);
            c2 = *(const float2*)(baseT + (size_t)(colbase + row0) * DD + 2 * lane);
#pragma unroll
            for (int j = 0; j < KK; ++j)
                u[j] = *(const float2*)(baseT + (size_t)nb[j] * DD + 2 * lane);
        }

#pragma unroll
        for (int i = 0; i < 8; ++i) {
            float2 c2n, un[KK];
            if (i < 7) {
                int nbn[KK];
#pragma unroll
                for (int j = 0; j < KK; ++j) nbn[j] = __shfl(iv, (i + 1) * 8 + j, 64);
                c2n = *(const float2*)(baseT + (size_t)(colbase + row0 + i + 1) * DD + 2 * lane);
#pragma unroll
                for (int j = 0; j < KK; ++j)
                    un[j] = *(const float2*)(baseT + (size_t)nbn[j] * DD + 2 * lane);
            }

            const int n_loc = row0 + i;
            const int n = colbase + n_loc;
            float gx = 0.0f, gy = 0.0f;
#pragma unroll
            for (int j = 0; j < KK; ++j) {
                gx += fmaxf(u[j].x, 0.0f);
                gy += fmaxf(u[j].y, 0.0f);
            }
            const float px = fmaxf(c2.x, 0.0f);
            const float py = fmaxf(c2.y, 0.0f);

            sc[n_loc][2 * lane]     = c2.x;
            sc[n_loc][2 * lane + 1] = c2.y;

            ushort phx = bf16_rn(px), phy = bf16_rn(py);
            ushort plx = bf16_rn(px - bf16_f(phx)), ply = bf16_rn(py - bf16_f(phy));
            ushort ghx = bf16_rn(gx), ghy = bf16_rn(gy);
            ushort glx = bf16_rn(gx - bf16_f(ghx)), gly = bf16_rn(gy - bf16_f(ghy));

            const int kP = 2 * lane;
            const int kG = 128 + 2 * lane;
            const int byP = n_loc * 512 + ((((kP >> 3) ^ (n_loc & 7))) << 4) + ((kP & 7) << 1);
            const int byG = n_loc * 512 + ((((kG >> 3) ^ (n_loc & 7))) << 4) + ((kG & 7) << 1);
            *(uint*)(xt_hi + byP) = (uint)phx | ((uint)phy << 16);
            *(uint*)(xt_lo + byP) = (uint)plx | ((uint)ply << 16);
            *(uint*)(xt_hi + byG) = (uint)ghx | ((uint)ghy << 16);
            *(uint*)(xt_lo + byG) = (uint)glx | ((uint)gly << 16);

            if (last) {   // fused unpool head
                float s0, s1, s2, s3, s4, s5;
                {
                    const int c0 = 2 * lane, c1 = 2 * lane + 1;
                    s0 = px * wc[0 * 128 + c0] + py * wc[0 * 128 + c1]
                       + gx * wn[0 * 128 + c0] + gy * wn[0 * 128 + c1];
                    s1 = px * wc[1 * 128 + c0] + py * wc[1 * 128 + c1]
                       + gx * wn[1 * 128 + c0] + gy * wn[1 * 128 + c1];
                    s2 = px * wc[2 * 128 + c0] + py * wc[2 * 128 + c1]
                       + gx * wn[2 * 128 + c0] + gy * wn[2 * 128 + c1];
                    s3 = px * wc[3 * 128 + c0] + py * wc[3 * 128 + c1]
                       + gx * wn[3 * 128 + c0] + gy * wn[3 * 128 + c1];
                    s4 = px * wc[4 * 128 + c0] + py * wc[4 * 128 + c1]
                       + gx * wn[4 * 128 + c0] + gy * wn[4 * 128 + c1];
                    s5 = px * wc[5 * 128 + c0] + py * wc[5 * 128 + c1]
                       + gx * wn[5 * 128 + c0] + gy * wn[5 * 128 + c1];
                }
#pragma unroll
                for (int st = 32; st; st >>= 1) {
                    s0 += __shfl_xor(s0, st, 64);
                    s1 += __shfl_xor(s1, st, 64);
                    s2 += __shfl_xor(s2, st, 64);
                    s3 += __shfl_xor(s3, st, 64);
                    s4 += __shfl_xor(s4, st, 64);
                    s5 += __shfl_xor(s5, st, 64);
                }
                if (lane < 6) {
                    float v = s0;
                    v = (lane == 1) ? s1 : v;
                    v = (lane == 2) ? s2 : v;
                    v = (lane == 3) ? s3 : v;
                    v = (lane == 4) ? s4 : v;
                    v = (lane == 5) ? s5 : v;
                    const int dd = lane >> 1, h = lane & 1;
                    const float xv = xyz[((size_t)b * 3 + dd) * NN + n];
                    out_xyz[(((size_t)b * 3 + dd) * 2 + h) * NN + n] =
                        v * (1.0f / 9.0f) + xv;
                }
            }

            if (i < 7) {
                c2 = c2n;
#pragma unroll
                for (int j = 0; j < KK; ++j) u[j] = un[j];
            }
        }
    }
    __syncthreads();

    // ---- phase B: MFMA. wave w: rows w*32..w*32+31, 2 ntiles
    const int ln15 = lane & 15;
    const int kl = lane >> 4;

    f32x4 acc[2][2] = {};
#pragma unroll
    for (int pass = 0; pass < 3; ++pass) {
        const ushort* Wp = (pass == 2) ? wlo : whi;
        const char* Xp = (pass == 1) ? xt_lo : xt_hi;
#pragma unroll
        for (int ks = 0; ks < 8; ++ks) {
            short8 a[2];
#pragma unroll
            for (int rt = 0; rt < 2; ++rt) {
                const int row = w * 32 + rt * 16 + ln15;
                a[rt] = *(const short8*)(Wp + (size_t)row * 256 + ks * 32 + kl * 8);
            }
            short8 bf[2];
#pragma unroll
            for (int nt = 0; nt < 2; ++nt) {
                const int n_loc = nt * 16 + ln15;
                const int by = n_loc * 512 + (((ks * 4 + kl) ^ (n_loc & 7)) << 4);
                bf[nt] = *(const short8*)(Xp + by);
            }
#pragma unroll
            for (int rt = 0; rt < 2; ++rt)
#pragma unroll
                for (int nt = 0; nt < 2; ++nt)
                    acc[rt][nt] = __builtin_amdgcn_mfma_f32_16x16x32_bf16(
                        a[rt], bf[nt], acc[rt][nt], 0, 0, 0);
        }
    }

    // ---- phase C: epilogue: out = acc/9 + shortcut (from LDS)
    const float inv = 1.0f / 9.0f;
#pragma unroll
    for (int rt = 0; rt < 2; ++rt) {
#pragma unroll
        for (int nt = 0; nt < 2; ++nt) {
            const int row = w * 32 + rt * 16 + (lane >> 4) * 4;
            const int nl = nt * 16 + ln15;
            const int n = colbase + nl;
            const float4 scv = *(const float4*)&sc[nl][row];
            float v0 = acc[rt][nt][0] * inv + scv.x;
            float v1 = acc[rt][nt][1] * inv + scv.y;
            float v2 = acc[rt][nt][2] * inv + scv.z;
            float v3 = acc[rt][nt][3] * inv + scv.w;
            if (!last) {
                *(float4*)(ptsT_out + ((size_t)b * NN + n) * DD + row) =
                    make_float4(v0, v1, v2, v3);
            } else {
                out_std[((size_t)b * DD + row + 0) * NN + n] = v0;
                out_std[((size_t)b * DD + row + 1) * NN + n] = v1;
                out_std[((size_t)b * DD + row + 2) * NN + n] = v2;
                out_std[((size_t)b * DD + row + 3) * NN + n] = v3;
            }
        }
    }
}

extern "C" void kernel_launch(void* const* d_in, const int* in_sizes, int n_in,
                              void* d_out, int out_size, void* d_ws, size_t ws_size,
                              hipStream_t stream) {
    const float* xyz    = (const float*)d_in[0];
    const float* points = (const float*)d_in[1];
    const float* w1     = (const float*)d_in[2];
    const float* w2     = (const float*)d_in[3];
    const float* wc     = (const float*)d_in[4];
    const float* wn     = (const float*)d_in[5];
    float* out = (float*)d_out;

    const size_t feat = (size_t)BB * DD * NN;          // 2,097,152 floats
    char* ws = (char*)d_ws;
    int*    idx  = (int*)ws;                            // 512 KB
    ushort* whi  = (ushort*)(ws + 524288);              // 768 KB
    ushort* wlo  = (ushort*)(ws + 524288 + 786432);     // 768 KB
    float*  pT0  = (float*)(ws + 524288 + 2 * 786432);  // 8 MB
    float*  pT1  = pT0 + feat;                          // 8 MB

    knn_kernel<<<dim3(NN / 8, BB), 512, 0, stream>>>(xyz, idx);
    prep_w<<<dim3(12 * 128 * 256 / 256), 256, 0, stream>>>(w1, w2, whi, wlo);
    transpose_pts<<<dim3(NN / 32, DD / 32, BB), 256, 0, stream>>>(points, pT0);

    float* out_pts = out + (size_t)BB * 3 * 2 * NN;
    float* bufs[2] = {pT0, pT1};
    for (int i = 0; i < NBLK; ++i) {
        const int last = (i == NBLK - 1);
        fused_block<<<dim3(512), 256, 0, stream>>>(
            bufs[i & 1], idx, whi + (size_t)i * 32768, wlo + (size_t)i * 32768,
            bufs[(i + 1) & 1], out_pts, wc, wn, xyz, out, last);
    }
}

// Round 11
// 326.893 us; speedup vs baseline: 1.0834x; 1.0834x over previous
//
#include <hip/hip_runtime.h>
#include <math.h>

#define BB 4
#define NN 4096
#define DD 128
#define KK 8
#define NBLK 12

typedef __attribute__((ext_vector_type(8))) short short8;
typedef __attribute__((ext_vector_type(4))) float f32x4;

__device__ inline ushort bf16_rn(float x) {
    uint u = __float_as_uint(x);
    u = (u + 0x7FFFu + ((u >> 16) & 1u)) >> 16;
    return (ushort)u;
}
__device__ inline float bf16_f(ushort h) { return __uint_as_float(((uint)h) << 16); }

// ---------------- kNN: two-pass threshold-gated exact selection -----------
// dist emulates reference f32: (sq[n] - 2*inner) + sq[m], RN, no FMA.
// Pass 1: per-lane top-2 (values only, branchless) -> t8 = 8th smallest of
//   the 128-value union (>= true global 8th: subset of real distances;
//   duplicate-collapse only raises it -> safe upper bound).
// Pass 2: rescan; only dist <= t8 (~10/query) enters the per-lane sorted-8
//   lexicographic insert. Union of per-lane top-8 always contains the global
//   top-8. Final butterfly merge = exact stable top_k order.
__global__ __launch_bounds__(512) void knn_kernel(const float* __restrict__ xyz,
                                                  int* __restrict__ idx) {
    __shared__ float xs[NN], ys[NN], zs[NN], sq[NN];
    const int b = blockIdx.y;
    const float* xb = xyz + (size_t)b * 3 * NN;
    for (int i = threadIdx.x; i < NN; i += 512) {
        float x = xb[i], y = xb[NN + i], z = xb[2 * NN + i];
        xs[i] = x; ys[i] = y; zs[i] = z;
        sq[i] = __fadd_rn(__fadd_rn(__fmul_rn(x, x), __fmul_rn(y, y)),
                          __fmul_rn(z, z));
    }
    __syncthreads();

    const int wave = threadIdx.x >> 6;
    const int lane = threadIdx.x & 63;
    const int n = blockIdx.x * 8 + wave;
    const float qx = xs[n], qy = ys[n], qz = zs[n], qsq = sq[n];

#define DIST(cx, cy, cz, cq)                                                  \
    __fadd_rn(__fsub_rn(qsq, __fmul_rn(2.0f,                                  \
        __fadd_rn(__fadd_rn(__fmul_rn(qx, (cx)), __fmul_rn(qy, (cy))),        \
                  __fmul_rn(qz, (cz))))), (cq))

    // ---- pass 1: per-lane top-2 (branchless, values only) ----
    float t0 = INFINITY, t1 = INFINITY;
    for (int j = 0; j < NN / 256; ++j) {
        const int m0 = j * 256 + lane * 4;
        const float4 vx = *(const float4*)&xs[m0];
        const float4 vy = *(const float4*)&ys[m0];
        const float4 vz = *(const float4*)&zs[m0];
        const float4 vq = *(const float4*)&sq[m0];
#pragma unroll
        for (int e = 0; e < 4; ++e) {
            float dist = DIST((&vx.x)[e], (&vy.x)[e], (&vz.x)[e], (&vq.x)[e]);
            const bool c1 = dist < t1;
            const float nt1 = c1 ? dist : t1;
            const bool c0 = dist < t0;
            t1 = c0 ? t0 : nt1;
            t0 = c0 ? dist : t0;
        }
    }
    // t8 = 8th extracted min of the union {t0,t1} x 64 lanes (upper bound)
    float t8;
#pragma unroll
    for (int it = 0; it < KK; ++it) {
        float hd = t0;
#pragma unroll
        for (int s = 32; s; s >>= 1) hd = fminf(hd, __shfl_xor(hd, s, 64));
        t8 = hd;
        if (t0 == hd) { t0 = t1; t1 = INFINITY; }
    }

    // ---- pass 2: gated exact collection ----
    float d[KK]; int id[KK];
#pragma unroll
    for (int j = 0; j < KK; ++j) { d[j] = INFINITY; id[j] = 0x7fffffff; }

    for (int j = 0; j < NN / 256; ++j) {
        const int m0 = j * 256 + lane * 4;
        const float4 vx = *(const float4*)&xs[m0];
        const float4 vy = *(const float4*)&ys[m0];
        const float4 vz = *(const float4*)&zs[m0];
        const float4 vq = *(const float4*)&sq[m0];
#pragma unroll
        for (int e = 0; e < 4; ++e) {
            float dist = DIST((&vx.x)[e], (&vy.x)[e], (&vz.x)[e], (&vq.x)[e]);
            const int m = m0 + e;
            const bool ins = (dist <= t8) &&
                             (dist < d[KK - 1] ||
                              (dist == d[KK - 1] && m < id[KK - 1]));
            if (__any(ins)) {                     // rare: ~10 steps per query
                if (ins) {
                    d[KK - 1] = dist; id[KK - 1] = m;
#pragma unroll
                    for (int t = KK - 1; t > 0; --t) {
                        bool sw = d[t] < d[t - 1] ||
                                  (d[t] == d[t - 1] && id[t] < id[t - 1]);
                        if (sw) {
                            float td = d[t]; d[t] = d[t - 1]; d[t - 1] = td;
                            int ti = id[t]; id[t] = id[t - 1]; id[t - 1] = ti;
                        }
                    }
                }
            }
        }
    }
#undef DIST

    // ---- exact stable merge: 8x extract global min by (dist, idx) ----
    int out[KK];
#pragma unroll
    for (int it = 0; it < KK; ++it) {
        float hd = d[0];
        int hi = id[0];
#pragma unroll
        for (int s = 32; s; s >>= 1) {
            float od = __shfl_xor(hd, s, 64);
            int oi = __shfl_xor(hi, s, 64);
            if (od < hd || (od == hd && oi < hi)) { hd = od; hi = oi; }
        }
        out[it] = hi;
        if (hd == d[0] && hi == id[0]) {
#pragma unroll
            for (int t = 0; t < KK - 1; ++t) { d[t] = d[t + 1]; id[t] = id[t + 1]; }
            d[KK - 1] = INFINITY; id[KK - 1] = 0x7fffffff;
        }
    }

    if (lane == 0) {
        int* op = idx + ((size_t)b * NN + n) * KK;
        *(int4*)op       = make_int4(out[0], out[1], out[2], out[3]);
        *(int4*)(op + 4) = make_int4(out[4], out[5], out[6], out[7]);
    }
}

// ---------------- weight prep: Wcat = [W1 | W2] split to bf16 hi/lo -------
__global__ __launch_bounds__(256) void prep_w(const float* __restrict__ w1,
                                              const float* __restrict__ w2,
                                              ushort* __restrict__ whi,
                                              ushort* __restrict__ wlo) {
    const int e = blockIdx.x * 256 + threadIdx.x;     // l*32768 + r*256 + k
    const int l = e >> 15;
    const int rem = e & 32767;
    const int r = rem >> 8;
    const int k = rem & 255;
    float w = (k < 128) ? w1[((size_t)l * 128 + r) * 128 + k]
                        : w2[((size_t)l * 128 + r) * 128 + (k - 128)];
    ushort h = bf16_rn(w);
    whi[e] = h;
    wlo[e] = bf16_rn(w - bf16_f(h));
}

// ---------------- initial transpose: ptsT[b][n][c] = points[b][c][n] ------
__global__ __launch_bounds__(256) void transpose_pts(const float* __restrict__ pts,
                                                     float* __restrict__ ptsT) {
    __shared__ float t[32][33];
    const int b = blockIdx.z;
    const int c0 = blockIdx.y * 32;
    const int n0 = blockIdx.x * 32;
    const int tx = threadIdx.x & 31;
    const int ty = threadIdx.x >> 5;
#pragma unroll
    for (int q = 0; q < 4; ++q)
        t[ty + 8 * q][tx] = pts[((size_t)b * DD + c0 + ty + 8 * q) * NN + n0 + tx];
    __syncthreads();
#pragma unroll
    for (int q = 0; q < 4; ++q)
        ptsT[((size_t)b * NN + n0 + ty + 8 * q) * DD + c0 + tx] = t[tx][ty + 8 * q];
}

// ---------------- fused: gather -> split bf16 -> MFMA -> residual ---------
// 32 cols x 128 rows per block, 256 threads (4 waves), grid 512 (2/CU).
__global__ __launch_bounds__(256) void fused_block(const float* __restrict__ ptsT_in,
                                                   const int* __restrict__ idx,
                                                   const ushort* __restrict__ whi,
                                                   const ushort* __restrict__ wlo,
                                                   float* __restrict__ ptsT_out,
                                                   float* __restrict__ out_std,
                                                   const float* __restrict__ wc,
                                                   const float* __restrict__ wn,
                                                   const float* __restrict__ xyz,
                                                   float* __restrict__ out_xyz,
                                                   const int last) {
    __shared__ __align__(16) char xt[32768];
    __shared__ float sc[32][132];
    char* xt_hi = xt;
    char* xt_lo = xt + 16384;

    const int bid = blockIdx.x;
    const int xcd = bid & 7;
    const int b = xcd >> 1;                         // 2 XCDs per batch
    const int colbase = (((xcd & 1) << 6) + (bid >> 3)) * 32;

    const int w = threadIdx.x >> 6;
    const int lane = threadIdx.x & 63;

    const float* baseT = ptsT_in + (size_t)b * NN * DD;

    // ---- phase A: pipelined gather, split, stage to LDS
    {
        const int row0 = w * 8;
        const int iv = idx[((size_t)b * NN + colbase + row0) * KK + lane];

        float2 c2, u[KK];
        {
            int nb[KK];
#pragma unroll
            for (int j = 0; j < KK; ++j) nb[j] = __shfl(iv, j, 64);
            c2 = *(const float2*)(baseT + (size_t)(colbase + row0) * DD + 2 * lane);
#pragma unroll
            for (int j = 0; j < KK; ++j)
                u[j] = *(const float2*)(baseT + (size_t)nb[j] * DD + 2 * lane);
        }

#pragma unroll
        for (int i = 0; i < 8; ++i) {
            float2 c2n, un[KK];
            if (i < 7) {
                int nbn[KK];
#pragma unroll
                for (int j = 0; j < KK; ++j) nbn[j] = __shfl(iv, (i + 1) * 8 + j, 64);
                c2n = *(const float2*)(baseT + (size_t)(colbase + row0 + i + 1) * DD + 2 * lane);
#pragma unroll
                for (int j = 0; j < KK; ++j)
                    un[j] = *(const float2*)(baseT + (size_t)nbn[j] * DD + 2 * lane);
            }

            const int n_loc = row0 + i;
            const int n = colbase + n_loc;
            float gx = 0.0f, gy = 0.0f;
#pragma unroll
            for (int j = 0; j < KK; ++j) {
                gx += fmaxf(u[j].x, 0.0f);
                gy += fmaxf(u[j].y, 0.0f);
            }
            const float px = fmaxf(c2.x, 0.0f);
            const float py = fmaxf(c2.y, 0.0f);

            sc[n_loc][2 * lane]     = c2.x;
            sc[n_loc][2 * lane + 1] = c2.y;

            ushort phx = bf16_rn(px), phy = bf16_rn(py);
            ushort plx = bf16_rn(px - bf16_f(phx)), ply = bf16_rn(py - bf16_f(phy));
            ushort ghx = bf16_rn(gx), ghy = bf16_rn(gy);
            ushort glx = bf16_rn(gx - bf16_f(ghx)), gly = bf16_rn(gy - bf16_f(ghy));

            const int kP = 2 * lane;
            const int kG = 128 + 2 * lane;
            const int byP = n_loc * 512 + ((((kP >> 3) ^ (n_loc & 7))) << 4) + ((kP & 7) << 1);
            const int byG = n_loc * 512 + ((((kG >> 3) ^ (n_loc & 7))) << 4) + ((kG & 7) << 1);
            *(uint*)(xt_hi + byP) = (uint)phx | ((uint)phy << 16);
            *(uint*)(xt_lo + byP) = (uint)plx | ((uint)ply << 16);
            *(uint*)(xt_hi + byG) = (uint)ghx | ((uint)ghy << 16);
            *(uint*)(xt_lo + byG) = (uint)glx | ((uint)gly << 16);

            if (last) {   // fused unpool head
                float s0, s1, s2, s3, s4, s5;
                {
                    const int c0 = 2 * lane, c1 = 2 * lane + 1;
                    s0 = px * wc[0 * 128 + c0] + py * wc[0 * 128 + c1]
                       + gx * wn[0 * 128 + c0] + gy * wn[0 * 128 + c1];
                    s1 = px * wc[1 * 128 + c0] + py * wc[1 * 128 + c1]
                       + gx * wn[1 * 128 + c0] + gy * wn[1 * 128 + c1];
                    s2 = px * wc[2 * 128 + c0] + py * wc[2 * 128 + c1]
                       + gx * wn[2 * 128 + c0] + gy * wn[2 * 128 + c1];
                    s3 = px * wc[3 * 128 + c0] + py * wc[3 * 128 + c1]
                       + gx * wn[3 * 128 + c0] + gy * wn[3 * 128 + c1];
                    s4 = px * wc[4 * 128 + c0] + py * wc[4 * 128 + c1]
                       + gx * wn[4 * 128 + c0] + gy * wn[4 * 128 + c1];
                    s5 = px * wc[5 * 128 + c0] + py * wc[5 * 128 + c1]
                       + gx * wn[5 * 128 + c0] + gy * wn[5 * 128 + c1];
                }
#pragma unroll
                for (int st = 32; st; st >>= 1) {
                    s0 += __shfl_xor(s0, st, 64);
                    s1 += __shfl_xor(s1, st, 64);
                    s2 += __shfl_xor(s2, st, 64);
                    s3 += __shfl_xor(s3, st, 64);
                    s4 += __shfl_xor(s4, st, 64);
                    s5 += __shfl_xor(s5, st, 64);
                }
                if (lane < 6) {
                    float v = s0;
                    v = (lane == 1) ? s1 : v;
                    v = (lane == 2) ? s2 : v;
                    v = (lane == 3) ? s3 : v;
                    v = (lane == 4) ? s4 : v;
                    v = (lane == 5) ? s5 : v;
                    const int dd = lane >> 1, h = lane & 1;
                    const float xv = xyz[((size_t)b * 3 + dd) * NN + n];
                    out_xyz[(((size_t)b * 3 + dd) * 2 + h) * NN + n] =
                        v * (1.0f / 9.0f) + xv;
                }
            }

            if (i < 7) {
                c2 = c2n;
#pragma unroll
                for (int j = 0; j < KK; ++j) u[j] = un[j];
            }
        }
    }
    __syncthreads();

    // ---- phase B: MFMA. wave w: rows w*32..w*32+31, 2 ntiles
    const int ln15 = lane & 15;
    const int kl = lane >> 4;

    f32x4 acc[2][2] = {};
#pragma unroll
    for (int pass = 0; pass < 3; ++pass) {
        const ushort* Wp = (pass == 2) ? wlo : whi;
        const char* Xp = (pass == 1) ? xt_lo : xt_hi;
#pragma unroll
        for (int ks = 0; ks < 8; ++ks) {
            short8 a[2];
#pragma unroll
            for (int rt = 0; rt < 2; ++rt) {
                const int row = w * 32 + rt * 16 + ln15;
                a[rt] = *(const short8*)(Wp + (size_t)row * 256 + ks * 32 + kl * 8);
            }
            short8 bf[2];
#pragma unroll
            for (int nt = 0; nt < 2; ++nt) {
                const int n_loc = nt * 16 + ln15;
                const int by = n_loc * 512 + (((ks * 4 + kl) ^ (n_loc & 7)) << 4);
                bf[nt] = *(const short8*)(Xp + by);
            }
#pragma unroll
            for (int rt = 0; rt < 2; ++rt)
#pragma unroll
                for (int nt = 0; nt < 2; ++nt)
                    acc[rt][nt] = __builtin_amdgcn_mfma_f32_16x16x32_bf16(
                        a[rt], bf[nt], acc[rt][nt], 0, 0, 0);
        }
    }

    // ---- phase C: epilogue: out = acc/9 + shortcut (from LDS)
    const float inv = 1.0f / 9.0f;
#pragma unroll
    for (int rt = 0; rt < 2; ++rt) {
#pragma unroll
        for (int nt = 0; nt < 2; ++nt) {
            const int row = w * 32 + rt * 16 + (lane >> 4) * 4;
            const int nl = nt * 16 + ln15;
            const int n = colbase + nl;
            const float4 scv = *(const float4*)&sc[nl][row];
            float v0 = acc[rt][nt][0] * inv + scv.x;
            float v1 = acc[rt][nt][1] * inv + scv.y;
            float v2 = acc[rt][nt][2] * inv + scv.z;
            float v3 = acc[rt][nt][3] * inv + scv.w;
            if (!last) {
                *(float4*)(ptsT_out + ((size_t)b * NN + n) * DD + row) =
                    make_float4(v0, v1, v2, v3);
            } else {
                out_std[((size_t)b * DD + row + 0) * NN + n] = v0;
                out_std[((size_t)b * DD + row + 1) * NN + n] = v1;
                out_std[((size_t)b * DD + row + 2) * NN + n] = v2;
                out_std[((size_t)b * DD + row + 3) * NN + n] = v3;
            }
        }
    }
}

extern "C" void kernel_launch(void* const* d_in, const int* in_sizes, int n_in,
                              void* d_out, int out_size, void* d_ws, size_t ws_size,
                              hipStream_t stream) {
    const float* xyz    = (const float*)d_in[0];
    const float* points = (const float*)d_in[1];
    const float* w1     = (const float*)d_in[2];
    const float* w2     = (const float*)d_in[3];
    const float* wc     = (const float*)d_in[4];
    const float* wn     = (const float*)d_in[5];
    float* out = (float*)d_out;

    const size_t feat = (size_t)BB * DD * NN;          // 2,097,152 floats
    char* ws = (char*)d_ws;
    int*    idx  = (int*)ws;                            // 512 KB
    ushort* whi  = (ushort*)(ws + 524288);              // 768 KB
    ushort* wlo  = (ushort*)(ws + 524288 + 786432);     // 768 KB
    float*  pT0  = (float*)(ws + 524288 + 2 * 786432);  // 8 MB
    float*  pT1  = pT0 + feat;                          // 8 MB

    knn_kernel<<<dim3(NN / 8, BB), 512, 0, stream>>>(xyz, idx);
    prep_w<<<dim3(12 * 128 * 256 / 256), 256, 0, stream>>>(w1, w2, whi, wlo);
    transpose_pts<<<dim3(NN / 32, DD / 32, BB), 256, 0, stream>>>(points, pT0);

    float* out_pts = out + (size_t)BB * 3 * 2 * NN;
    float* bufs[2] = {pT0, pT1};
    for (int i = 0; i < NBLK; ++i) {
        const int last = (i == NBLK - 1);
        fused_block<<<dim3(512), 256, 0, stream>>>(
            bufs[i & 1], idx, whi + (size_t)i * 32768, wlo + (size_t)i * 32768,
            bufs[(i + 1) & 1], out_pts, wc, wn, xyz, out, last);
    }
}

// Round 13
// 296.269 us; speedup vs baseline: 1.1953x; 1.1034x over previous
//
#include <hip/hip_runtime.h>
#include <math.h>

#define BB 4
#define NN 4096
#define DD 128
#define KK 8
#define NBLK 12

typedef __attribute__((ext_vector_type(8))) short short8;
typedef __attribute__((ext_vector_type(4))) float f32x4;

__device__ inline ushort bf16_rn(float x) {
    uint u = __float_as_uint(x);
    u = (u + 0x7FFFu + ((u >> 16) & 1u)) >> 16;
    return (ushort)u;
}
__device__ inline float bf16_f(ushort h) { return __uint_as_float(((uint)h) << 16); }

// ---------------- kNN (R3-exact version: 112us known-good) ----------------
__global__ __launch_bounds__(512) void knn_kernel(const float* __restrict__ xyz,
                                                  int* __restrict__ idx) {
    __shared__ float xs[NN], ys[NN], zs[NN], sq[NN];
    const int b = blockIdx.y;
    const float* xb = xyz + (size_t)b * 3 * NN;
    for (int i = threadIdx.x; i < NN; i += 512) {
        float x = xb[i], y = xb[NN + i], z = xb[2 * NN + i];
        xs[i] = x; ys[i] = y; zs[i] = z;
        sq[i] = __fadd_rn(__fadd_rn(__fmul_rn(x, x), __fmul_rn(y, y)),
                          __fmul_rn(z, z));
    }
    __syncthreads();

    const int wave = threadIdx.x >> 6;
    const int lane = threadIdx.x & 63;
    const int n = blockIdx.x * 8 + wave;
    const float qx = xs[n], qy = ys[n], qz = zs[n], qsq = sq[n];

    float d[KK];
    int id[KK];
#pragma unroll
    for (int j = 0; j < KK; ++j) { d[j] = INFINITY; id[j] = -1; }

    for (int j = 0; j < NN / 256; ++j) {
        const int m0 = j * 256 + lane * 4;
        const float4 vx = *(const float4*)&xs[m0];
        const float4 vy = *(const float4*)&ys[m0];
        const float4 vz = *(const float4*)&zs[m0];
        const float4 vq = *(const float4*)&sq[m0];
#pragma unroll
        for (int e = 0; e < 4; ++e) {
            const float cx = (&vx.x)[e], cy = (&vy.x)[e], cz = (&vz.x)[e];
            const float cq = (&vq.x)[e];
            float inner = __fadd_rn(__fadd_rn(__fmul_rn(qx, cx),
                                              __fmul_rn(qy, cy)),
                                    __fmul_rn(qz, cz));
            float dist = __fadd_rn(__fsub_rn(qsq, __fmul_rn(2.0f, inner)), cq);
            if (dist < d[KK - 1]) {
                d[KK - 1] = dist; id[KK - 1] = m0 + e;
#pragma unroll
                for (int t = KK - 1; t > 0; --t) {
                    if (d[t] < d[t - 1]) {
                        float td = d[t]; d[t] = d[t - 1]; d[t - 1] = td;
                        int ti = id[t]; id[t] = id[t - 1]; id[t - 1] = ti;
                    }
                }
            }
        }
    }

    int out[KK];
#pragma unroll
    for (int it = 0; it < KK; ++it) {
        float hd = d[0];
        int hi = id[0];
#pragma unroll
        for (int s = 32; s; s >>= 1) {
            float od = __shfl_xor(hd, s, 64);
            int oi = __shfl_xor(hi, s, 64);
            if (od < hd || (od == hd && oi < hi)) { hd = od; hi = oi; }
        }
        out[it] = hi;
        if (hd == d[0] && hi == id[0]) {
#pragma unroll
            for (int t = 0; t < KK - 1; ++t) { d[t] = d[t + 1]; id[t] = id[t + 1]; }
            d[KK - 1] = INFINITY; id[KK - 1] = -1;
        }
    }

    if (lane == 0) {
        int* op = idx + ((size_t)b * NN + n) * KK;
        *(int4*)op       = make_int4(out[0], out[1], out[2], out[3]);
        *(int4*)(op + 4) = make_int4(out[4], out[5], out[6], out[7]);
    }
}

// ---------------- weight prep: Wcat = [W1 | W2] split to bf16 hi/lo -------
__global__ __launch_bounds__(256) void prep_w(const float* __restrict__ w1,
                                              const float* __restrict__ w2,
                                              ushort* __restrict__ whi,
                                              ushort* __restrict__ wlo) {
    const int e = blockIdx.x * 256 + threadIdx.x;     // l*32768 + r*256 + k
    const int l = e >> 15;
    const int rem = e & 32767;
    const int r = rem >> 8;
    const int k = rem & 255;
    float w = (k < 128) ? w1[((size_t)l * 128 + r) * 128 + k]
                        : w2[((size_t)l * 128 + r) * 128 + (k - 128)];
    ushort h = bf16_rn(w);
    whi[e] = h;
    wlo[e] = bf16_rn(w - bf16_f(h));
}

// ---------------- initial transpose: ptsT[b][n][c] = points[b][c][n] ------
__global__ __launch_bounds__(256) void transpose_pts(const float* __restrict__ pts,
                                                     float* __restrict__ ptsT) {
    __shared__ float t[32][33];
    const int b = blockIdx.z;
    const int c0 = blockIdx.y * 32;
    const int n0 = blockIdx.x * 32;
    const int tx = threadIdx.x & 31;
    const int ty = threadIdx.x >> 5;
#pragma unroll
    for (int q = 0; q < 4; ++q)
        t[ty + 8 * q][tx] = pts[((size_t)b * DD + c0 + ty + 8 * q) * NN + n0 + tx];
    __syncthreads();
#pragma unroll
    for (int q = 0; q < 4; ++q)
        ptsT[((size_t)b * NN + n0 + ty + 8 * q) * DD + c0 + tx] = t[tx][ty + 8 * q];
}

// ---------------- fused: gather -> split bf16 -> MFMA -> residual ---------
// 32 cols x 128 rows per block, 512 threads (8 waves), grid 512 (2/CU,
// 16 waves/CU). Phase A: float4 gather, 2 rows/step/wave, 2 steps.
// Phase B: per-ks fused 3-combo MFMA (W hi/lo each read once).
__global__ __launch_bounds__(512, 4) void fused_block(const float* __restrict__ ptsT_in,
                                                      const int* __restrict__ idx,
                                                      const ushort* __restrict__ whi,
                                                      const ushort* __restrict__ wlo,
                                                      float* __restrict__ ptsT_out,
                                                      float* __restrict__ out_std,
                                                      const float* __restrict__ wc,
                                                      const float* __restrict__ wn,
                                                      const float* __restrict__ xyz,
                                                      float* __restrict__ out_xyz,
                                                      const int last) {
    __shared__ __align__(16) char xt[32768];
    __shared__ float sc[32][132];
    char* xt_hi = xt;
    char* xt_lo = xt + 16384;

    const int bid = blockIdx.x;
    const int xcd = bid & 7;
    const int b = xcd >> 1;                         // 2 XCDs per batch
    const int colbase = (((xcd & 1) << 6) + (bid >> 3)) * 32;

    const int w = threadIdx.x >> 6;                 // 0..7
    const int lane = threadIdx.x & 63;
    const int half = lane >> 5;                     // row within pair
    const int l32 = lane & 31;                      // channel group (4 ch)
    const int choff = 4 * l32;
    const int row0 = w * 4;                         // wave owns 4 rows

    const float* baseT = ptsT_in + (size_t)b * NN * DD;

    // idx for this wave's 4 rows (32 ints, duplicated across lane halves)
    const int iv = idx[((size_t)b * NN + colbase + row0) * KK + (lane & 31)];

    const int ln15 = lane & 15;
    const int kl = lane >> 4;

    // ---- phase A: gather (float4, 2 rows/step, 2 steps) ----
#pragma unroll
    for (int i = 0; i < 2; ++i) {
        const int n_loc = row0 + 2 * i + half;
        const int n = colbase + n_loc;

        int nb[KK];
#pragma unroll
        for (int j = 0; j < KK; ++j) nb[j] = __shfl(iv, (2 * i + half) * 8 + j, 64);

        const float4 c4 = *(const float4*)(baseT + (size_t)n * DD + choff);
        float4 u[KK];
#pragma unroll
        for (int j = 0; j < KK; ++j)
            u[j] = *(const float4*)(baseT + (size_t)nb[j] * DD + choff);

        float g0 = 0.f, g1 = 0.f, g2 = 0.f, g3 = 0.f;
#pragma unroll
        for (int j = 0; j < KK; ++j) {
            g0 += fmaxf(u[j].x, 0.f);
            g1 += fmaxf(u[j].y, 0.f);
            g2 += fmaxf(u[j].z, 0.f);
            g3 += fmaxf(u[j].w, 0.f);
        }
        const float p0 = fmaxf(c4.x, 0.f);
        const float p1 = fmaxf(c4.y, 0.f);
        const float p2 = fmaxf(c4.z, 0.f);
        const float p3 = fmaxf(c4.w, 0.f);

        *(float4*)&sc[n_loc][choff] = c4;           // shortcut cache (pre-relu)

        ushort ph0 = bf16_rn(p0), ph1 = bf16_rn(p1), ph2 = bf16_rn(p2), ph3 = bf16_rn(p3);
        ushort pl0 = bf16_rn(p0 - bf16_f(ph0)), pl1 = bf16_rn(p1 - bf16_f(ph1));
        ushort pl2 = bf16_rn(p2 - bf16_f(ph2)), pl3 = bf16_rn(p3 - bf16_f(ph3));
        ushort gh0 = bf16_rn(g0), gh1 = bf16_rn(g1), gh2 = bf16_rn(g2), gh3 = bf16_rn(g3);
        ushort gl0 = bf16_rn(g0 - bf16_f(gh0)), gl1 = bf16_rn(g1 - bf16_f(gh1));
        ushort gl2 = bf16_rn(g2 - bf16_f(gh2)), gl3 = bf16_rn(g3 - bf16_f(gh3));

        const int gP = l32 >> 1;                    // granule 0..15 (P half)
        const int sub = (l32 & 1) << 3;             // byte 0 or 8 in granule
        const int byP = n_loc * 512 + ((gP ^ (n_loc & 7)) << 4) + sub;
        const int byG = n_loc * 512 + (((16 + gP) ^ (n_loc & 7)) << 4) + sub;

        *(unsigned long long*)(xt_hi + byP) =
            (unsigned long long)ph0 | ((unsigned long long)ph1 << 16) |
            ((unsigned long long)ph2 << 32) | ((unsigned long long)ph3 << 48);
        *(unsigned long long*)(xt_lo + byP) =
            (unsigned long long)pl0 | ((unsigned long long)pl1 << 16) |
            ((unsigned long long)pl2 << 32) | ((unsigned long long)pl3 << 48);
        *(unsigned long long*)(xt_hi + byG) =
            (unsigned long long)gh0 | ((unsigned long long)gh1 << 16) |
            ((unsigned long long)gh2 << 32) | ((unsigned long long)gh3 << 48);
        *(unsigned long long*)(xt_lo + byG) =
            (unsigned long long)gl0 | ((unsigned long long)gl1 << 16) |
            ((unsigned long long)gl2 << 32) | ((unsigned long long)gl3 << 48);

        if (last) {                                 // fused unpool head
            float s0, s1, s2, s3, s4, s5;
            {
                const int c0 = choff, c1 = choff + 1, c2 = choff + 2, c3 = choff + 3;
                s0 = p0 * wc[0 * 128 + c0] + p1 * wc[0 * 128 + c1] + p2 * wc[0 * 128 + c2] + p3 * wc[0 * 128 + c3]
                   + g0 * wn[0 * 128 + c0] + g1 * wn[0 * 128 + c1] + g2 * wn[0 * 128 + c2] + g3 * wn[0 * 128 + c3];
                s1 = p0 * wc[1 * 128 + c0] + p1 * wc[1 * 128 + c1] + p2 * wc[1 * 128 + c2] + p3 * wc[1 * 128 + c3]
                   + g0 * wn[1 * 128 + c0] + g1 * wn[1 * 128 + c1] + g2 * wn[1 * 128 + c2] + g3 * wn[1 * 128 + c3];
                s2 = p0 * wc[2 * 128 + c0] + p1 * wc[2 * 128 + c1] + p2 * wc[2 * 128 + c2] + p3 * wc[2 * 128 + c3]
                   + g0 * wn[2 * 128 + c0] + g1 * wn[2 * 128 + c1] + g2 * wn[2 * 128 + c2] + g3 * wn[2 * 128 + c3];
                s3 = p0 * wc[3 * 128 + c0] + p1 * wc[3 * 128 + c1] + p2 * wc[3 * 128 + c2] + p3 * wc[3 * 128 + c3]
                   + g0 * wn[3 * 128 + c0] + g1 * wn[3 * 128 + c1] + g2 * wn[3 * 128 + c2] + g3 * wn[3 * 128 + c3];
                s4 = p0 * wc[4 * 128 + c0] + p1 * wc[4 * 128 + c1] + p2 * wc[4 * 128 + c2] + p3 * wc[4 * 128 + c3]
                   + g0 * wn[4 * 128 + c0] + g1 * wn[4 * 128 + c1] + g2 * wn[4 * 128 + c2] + g3 * wn[4 * 128 + c3];
                s5 = p0 * wc[5 * 128 + c0] + p1 * wc[5 * 128 + c1] + p2 * wc[5 * 128 + c2] + p3 * wc[5 * 128 + c3]
                   + g0 * wn[5 * 128 + c0] + g1 * wn[5 * 128 + c1] + g2 * wn[5 * 128 + c2] + g3 * wn[5 * 128 + c3];
            }
#pragma unroll
            for (int st = 16; st; st >>= 1) {       // reduce within 32-lane group
                s0 += __shfl_xor(s0, st, 64);
                s1 += __shfl_xor(s1, st, 64);
                s2 += __shfl_xor(s2, st, 64);
                s3 += __shfl_xor(s3, st, 64);
                s4 += __shfl_xor(s4, st, 64);
                s5 += __shfl_xor(s5, st, 64);
            }
            if (l32 < 6) {
                float v = s0;
                v = (l32 == 1) ? s1 : v;
                v = (l32 == 2) ? s2 : v;
                v = (l32 == 3) ? s3 : v;
                v = (l32 == 4) ? s4 : v;
                v = (l32 == 5) ? s5 : v;
                const int dd = l32 >> 1, h = l32 & 1;
                const float xv = xyz[((size_t)b * 3 + dd) * NN + n];
                out_xyz[(((size_t)b * 3 + dd) * 2 + h) * NN + n] =
                    v * (1.0f / 9.0f) + xv;
            }
        }
    }
    __syncthreads();

    // ---- phase B: MFMA. wave w: rows w*16..w*16+15, 2 ntiles,
    //      per-ks fused 3-combo (a_hi*x_hi + a_hi*x_lo + a_lo*x_hi) ----
    const int wrow = w * 16 + ln15;
    f32x4 acc[2] = {};
#pragma unroll
    for (int ks = 0; ks < 8; ++ks) {
        const short8 a_hi = *(const short8*)(whi + (size_t)wrow * 256 + ks * 32 + kl * 8);
        const short8 a_lo = *(const short8*)(wlo + (size_t)wrow * 256 + ks * 32 + kl * 8);
        short8 bfh[2], bfl[2];
#pragma unroll
        for (int nt = 0; nt < 2; ++nt) {
            const int n_loc = nt * 16 + ln15;
            const int by = n_loc * 512 + (((ks * 4 + kl) ^ (n_loc & 7)) << 4);
            bfh[nt] = *(const short8*)(xt_hi + by);
            bfl[nt] = *(const short8*)(xt_lo + by);
        }
#pragma unroll
        for (int nt = 0; nt < 2; ++nt) {
            acc[nt] = __builtin_amdgcn_mfma_f32_16x16x32_bf16(a_hi, bfh[nt], acc[nt], 0, 0, 0);
            acc[nt] = __builtin_amdgcn_mfma_f32_16x16x32_bf16(a_hi, bfl[nt], acc[nt], 0, 0, 0);
            acc[nt] = __builtin_amdgcn_mfma_f32_16x16x32_bf16(a_lo, bfh[nt], acc[nt], 0, 0, 0);
        }
    }

    // ---- phase C: epilogue: out = acc/9 + shortcut (from LDS) ----
    const float inv = 1.0f / 9.0f;
    const int orow = w * 16 + kl * 4;
#pragma unroll
    for (int nt = 0; nt < 2; ++nt) {
        const int nl = nt * 16 + ln15;
        const int n = colbase + nl;
        const float4 scv = *(const float4*)&sc[nl][orow];
        float v0 = acc[nt][0] * inv + scv.x;
        float v1 = acc[nt][1] * inv + scv.y;
        float v2 = acc[nt][2] * inv + scv.z;
        float v3 = acc[nt][3] * inv + scv.w;
        if (!last) {
            *(float4*)(ptsT_out + ((size_t)b * NN + n) * DD + orow) =
                make_float4(v0, v1, v2, v3);
        } else {
            out_std[((size_t)b * DD + orow + 0) * NN + n] = v0;
            out_std[((size_t)b * DD + orow + 1) * NN + n] = v1;
            out_std[((size_t)b * DD + orow + 2) * NN + n] = v2;
            out_std[((size_t)b * DD + orow + 3) * NN + n] = v3;
        }
    }
}

extern "C" void kernel_launch(void* const* d_in, const int* in_sizes, int n_in,
                              void* d_out, int out_size, void* d_ws, size_t ws_size,
                              hipStream_t stream) {
    const float* xyz    = (const float*)d_in[0];
    const float* points = (const float*)d_in[1];
    const float* w1     = (const float*)d_in[2];
    const float* w2     = (const float*)d_in[3];
    const float* wc     = (const float*)d_in[4];
    const float* wn     = (const float*)d_in[5];
    float* out = (float*)d_out;

    const size_t feat = (size_t)BB * DD * NN;          // 2,097,152 floats
    char* ws = (char*)d_ws;
    int*    idx  = (int*)ws;                            // 512 KB
    ushort* whi  = (ushort*)(ws + 524288);              // 768 KB
    ushort* wlo  = (ushort*)(ws + 524288 + 786432);     // 768 KB
    float*  pT0  = (float*)(ws + 524288 + 2 * 786432);  // 8 MB
    float*  pT1  = pT0 + feat;                          // 8 MB

    knn_kernel<<<dim3(NN / 8, BB), 512, 0, stream>>>(xyz, idx);
    prep_w<<<dim3(12 * 128 * 256 / 256), 256, 0, stream>>>(w1, w2, whi, wlo);
    transpose_pts<<<dim3(NN / 32, DD / 32, BB), 256, 0, stream>>>(points, pT0);

    float* out_pts = out + (size_t)BB * 3 * 2 * NN;
    float* bufs[2] = {pT0, pT1};
    for (int i = 0; i < NBLK; ++i) {
        const int last = (i == NBLK - 1);
        fused_block<<<dim3(512), 512, 0, stream>>>(
            bufs[i & 1], idx, whi + (size_t)i * 32768, wlo + (size_t)i * 32768,
            bufs[(i + 1) & 1], out_pts, wc, wn, xyz, out, last);
    }
}